// Round 2
// baseline (383.907 us; speedup 1.0000x reference)
//
#include <hip/hip_runtime.h>
#include <stdint.h>

typedef unsigned short ushort_t;
typedef __bf16 bf16x8 __attribute__((ext_vector_type(8)));
typedef float  f32x4  __attribute__((ext_vector_type(4)));

#define DEV static __device__ __forceinline__

// fp32 -> bf16 round-to-nearest-even
DEV ushort_t f2bf(float f){
  union { float f; unsigned u; } x; x.f = f;
  unsigned u = x.u;
  return (ushort_t)((u + 0x7fffu + ((u >> 16) & 1u)) >> 16);
}

// Boustrophedon map for S=8192 (g=91): involution, maps permuted<->original.
DEV int hmap(int p){
  int r = p / 91;
  int c = p - r * 91;
  return (r & 1) ? (r * 91 + 90 - c) : p;
}

// A-row gather modes: 0 identity; 1 = Q permuted order (row p of batch b reads
// natural row hmap(p)); 2 = compacted dilated KV order (row seg*64+j of batch b
// reads natural row hmap(seg*128+2j)).
template<int GATHER>
DEV int arow_map(int r){
  if (GATHER == 0) return r;
  if (GATHER == 1){ int b = r >> 13, p = r & 8191; return b * 8192 + hmap(p); }
  int b = r >> 12, rem = r & 4095, seg = rem >> 6, j = rem & 63;
  return b * 8192 + hmap(seg * 128 + 2 * j);
}

// ---------------- cast x (fp32 -> bf16), vectorized ----------------
__global__ void cast_kernel(const float* __restrict__ in, ushort_t* __restrict__ out, int n4){
  int i = blockIdx.x * blockDim.x + threadIdx.x;
  if (i < n4){
    float4 v = ((const float4*)in)[i];
    ushort4 o;
    o.x = f2bf(v.x); o.y = f2bf(v.y); o.z = f2bf(v.z); o.w = f2bf(v.w);
    ((ushort4*)out)[i] = o;
  }
}

// ---------- transpose + cast: W [rows][cols] fp32 -> WT [cols][rows] bf16 ----------
__global__ void transpose_cast(const float* __restrict__ W, ushort_t* __restrict__ WT,
                               int rows, int cols){
  __shared__ ushort_t t[64 * 66];   // pad 66: conflict-free column reads
  int tid = threadIdx.x;
  int c0 = blockIdx.x * 64, r0 = blockIdx.y * 64;
  int cl = tid & 63, rb = tid >> 6;
  for (int i = 0; i < 16; ++i){
    int r = rb + i * 4;
    t[r * 66 + cl] = f2bf(W[(size_t)(r0 + r) * cols + c0 + cl]);
  }
  __syncthreads();
  int rr = tid & 63, cb = tid >> 6;
  for (int i = 0; i < 16; ++i){
    int cc = cb + i * 4;
    WT[(size_t)(c0 + cc) * rows + r0 + rr] = t[rr * 66 + cc];
  }
}

// ================= 256x256 reg-staged 1-barrier GEMM =================
// C[M][N] = A[gather(M)][K] * BT[N][K]^T, BM=BN=256, BK=64, 512 thr (8 waves,
// 2Mx4N, each wave 128x64). LDS = 2 dbuf x (A 32KB + B 32KB) = 128 KiB.
//
// R1 post-mortem: 8-phase with global_load_lds was a NULL (MfmaUtil 26.7%,
// dur identical to the 2-barrier loop). Hypothesis: the compiler's waitcnt
// pass treats LDS-DMA (global_load_lds) as a hazard for any ds_read it can't
// prove disjoint -> inserts vmcnt drains every phase, collapsing the pipeline.
//
// This version stages through REGISTERS (T14): global_load_dwordx4 -> VGPR ->
// ds_write_b128. vmcnt now tracks register loads with exact deps (compiler
// emits precise counted waits, no LDS aliasing problem). Schedule per tile t:
//   COMPUTE(t)  : 24 ds_read_b128 + 64 MFMA, compiler co-scheduled
//   WRITE(t+1)  : 8 ds_write_b128 of regs (loads issued one full tile ago,
//                 ~3000cy > 900cy HBM latency -> vmcnt wait is ~free)
//   LOAD(t+2)   : 8 global_load_dwordx4 -> regs (issue-early, T14)
//   lgkmcnt(0); s_barrier            // ONE barrier per K-tile
// Hazards: WRITE(t+1) targets buf[(t+1)&1] whose readers (tile t-1) drained
// at the t-1 barrier; COMPUTE(t) reads buf[t&1] written before the t-1
// barrier. Loads can't sink past the asm barrier (memory clobber) -> issue
// point guaranteed before it.
//
// LDS swizzle on the WRITE side now: row r, global chunk c (16B) lands at
// slot c^(r&7); global reads are fully linear. Fragment reads use same XOR.
// XCD chunk covers mt-range x ALL nt -> each A panel is fetched by exactly
// one XCD (fixes R1's FETCH amplification 24.6->67.6 MB).

#define LGKM0()   asm volatile("s_waitcnt lgkmcnt(0)" ::: "memory")
#define BARRIER() asm volatile("s_barrier" ::: "memory")

#define LOAD(T)                                                                \
  {                                                                            \
    _Pragma("unroll") for (int i = 0; i < 4; ++i){                             \
      ra[i] = *(const uint4*)&A [asrcR[i] + (size_t)(T) * 64];                 \
      rb[i] = *(const uint4*)&BT[bsrcR[i] + (size_t)(T) * 64];                 \
    }                                                                          \
  }

#define WRITE(T)                                                               \
  {                                                                            \
    ushort_t* d_ = &smem[(((T) & 1) << 15) + rbase * 64 + wsl];                \
    _Pragma("unroll") for (int i = 0; i < 4; ++i){                             \
      *(uint4*)&d_[i * 4096]         = ra[i];                                  \
      *(uint4*)&d_[16384 + i * 4096] = rb[i];                                  \
    }                                                                          \
  }

template<int OUT_BF16, int GATHER>
__global__ __launch_bounds__(512, 2) void gemm_bt(const ushort_t* __restrict__ A,
                                                  const ushort_t* __restrict__ BT,
                                                  void* __restrict__ Cout,
                                                  int M, int N, int K){
  __shared__ __align__(16) ushort_t smem[65536];   // 128 KiB
  const int NT = K >> 6;                           // K-tiles (=16)
  int tid = threadIdx.x;
  int lane = tid & 63, w = tid >> 6;
  int md = lane & 15, qd = lane >> 4;
  int wm = w >> 2, wn = w & 3;

  // XCD chunking: nwg=256 (1 block/CU). Chunk = one XCD = 32 blocks covering
  // (32/ntc) mt-values x all ntc nt-values -> each A panel stays on one XCD.
  int orig = blockIdx.x;
  int xcd = orig & 7, local = orig >> 3;           // local 0..31
  int ntc = N >> 8;                                // 4 or 8
  int ls  = (ntc == 8) ? 3 : 2;
  int nt  = local & (ntc - 1);
  int mt  = xcd * (32 >> ls) + (local >> ls);
  int m0 = mt << 8, n0 = nt << 8;

  // staging addressing: thread covers rows r_i = i*64 + rbase, global chunk
  // cch (linear!); LDS slot = cch ^ (r&7); (64*i)&7==0 so slot is i-indep.
  int rbase = tid >> 3, cch = tid & 7;
  int wsl = (cch ^ (rbase & 7)) * 8;               // swizzled write slot (elems)
  size_t asrcR[4], bsrcR[4];
  #pragma unroll
  for (int i = 0; i < 4; ++i){
    asrcR[i] = (size_t)arow_map<GATHER>(m0 + i * 64 + rbase) * K + cch * 8;
    bsrcR[i] = (size_t)(n0 + i * 64 + rbase) * K + cch * 8;
  }

  // fragment offsets: frag row = (multiple of 8) + md -> row&7 == md&7
  int axor[2] = { (qd ^ (md & 7)) * 8, ((4 + qd) ^ (md & 7)) * 8 };
  int abase = (wm * 128 + md) * 64;
  int bbase = 16384 + (wn * 64 + md) * 64;

  f32x4 acc[8][4];
  #pragma unroll
  for (int a = 0; a < 8; ++a)
    #pragma unroll
    for (int b = 0; b < 4; ++b)
      #pragma unroll
      for (int e = 0; e < 4; ++e) acc[a][b][e] = 0.f;

  uint4 ra[4], rb[4];

  // prologue: tile0 -> regs -> LDS; tile1 -> regs
  LOAD(0);
  WRITE(0);          // compiler inserts exact vmcnt waits before each use
  LOAD(1);
  LGKM0(); BARRIER();

  for (int t = 0; t < NT; ++t){
    const ushort_t* Ab = &smem[((t & 1) << 15) + abase];
    const ushort_t* Bb = &smem[((t & 1) << 15) + bbase];

    #pragma unroll
    for (int kk = 0; kk < 2; ++kk){
      bf16x8 bg[4];
      #pragma unroll
      for (int ni = 0; ni < 4; ++ni)
        bg[ni] = *(const bf16x8*)&Bb[ni * 1024 + axor[kk]];
      #pragma unroll
      for (int mi = 0; mi < 8; ++mi){
        bf16x8 af = *(const bf16x8*)&Ab[mi * 1024 + axor[kk]];
        #pragma unroll
        for (int ni = 0; ni < 4; ++ni)
          acc[mi][ni] = __builtin_amdgcn_mfma_f32_16x16x32_bf16(af, bg[ni], acc[mi][ni], 0, 0, 0);
      }
    }

    if (t + 1 < NT) WRITE(t + 1);
    if (t + 2 < NT) LOAD(t + 2);
    LGKM0(); BARRIER();
  }

  // epilogue: 16x16 C/D layout col=lane&15, row=(lane>>4)*4+reg
  int crow0 = m0 + wm * 128 + qd * 4;
  int ccol0 = n0 + wn * 64 + md;
  #pragma unroll
  for (int mi = 0; mi < 8; ++mi){
    #pragma unroll
    for (int ni = 0; ni < 4; ++ni){
      f32x4 v = acc[mi][ni];
      #pragma unroll
      for (int r = 0; r < 4; ++r){
        size_t idx = (size_t)(crow0 + mi * 16 + r) * N + ccol0 + ni * 16;
        if (OUT_BF16) ((ushort_t*)Cout)[idx] = f2bf(v[r]);
        else          ((float*)   Cout)[idx] = v[r];
      }
    }
  }
}

// ---------------- fused segment attention ----------------
// grid (nseg=64, H=16, B=2), block 256 (4 waves).
// Qb:  [B*8192][1024] bf16, rows already in PERMUTED order (gemm1a GATHER=1).
// KV:  [B*4096][2048] bf16, rows in compacted dilated order seg*64+j
//      (gemm1b GATHER=2); cols 0..1023 = K, 1024..2047 = V.
// All loads contiguous; O goes through LDS so global stores are 16B coalesced;
// only the O row index applies hmap (involution inverse).
__global__ __launch_bounds__(256) void attn_kernel(const ushort_t* __restrict__ Qb,
                                                   const ushort_t* __restrict__ KV,
                                                   ushort_t* __restrict__ aout){
  __shared__ ushort_t Qs[128 * 72];   // reused as P, then as O (wave-private rows)
  __shared__ ushort_t Ks[64 * 72];
  __shared__ ushort_t Vt[64 * 72];    // V transposed: Vt[d][kidx]
  int tid  = threadIdx.x;
  int lane = tid & 63, w = tid >> 6;
  int qd = lane >> 4, md = lane & 15;
  int seg = blockIdx.x, h = blockIdx.y, b = blockIdx.z;
  int p0 = seg * 128;

  // Q: 128 rows x 64 bf16 (8 chunks of 16B per row), contiguous rows
  for (int it = 0; it < 4; ++it){
    int q = it * 256 + tid;
    int r = q >> 3, ch = q & 7;
    uint4 d = *(const uint4*)&Qb[(size_t)(b * 8192 + p0 + r) * 1024 + h * 64 + ch * 8];
    *(uint4*)&Qs[r * 72 + ch * 8] = d;
  }
  // K: compacted rows seg*64 + r
  for (int it = 0; it < 2; ++it){
    int q = it * 256 + tid;
    int r = q >> 3, ch = q & 7;
    uint4 d = *(const uint4*)&KV[(size_t)(b * 4096 + seg * 64 + r) * 2048 + h * 64 + ch * 8];
    *(uint4*)&Ks[r * 72 + ch * 8] = d;
  }
  // V (cols 1024..2047), stored transposed for the PV B-operand
  for (int it = 0; it < 2; ++it){
    int q = it * 256 + tid;
    int r = q >> 3, ch = q & 7;
    union { uint4 v; ushort_t u[8]; } d;
    d.v = *(const uint4*)&KV[(size_t)(b * 4096 + seg * 64 + r) * 2048 + 1024 + h * 64 + ch * 8];
    for (int e = 0; e < 8; ++e) Vt[(ch * 8 + e) * 72 + r] = d.u[e];
  }
  __syncthreads();

  // scores: wave w owns q-rows [32w, 32w+32): 2 row-tiles x 4 col-tiles
  f32x4 z = {0.f, 0.f, 0.f, 0.f};
  f32x4 sc[2][4];
  for (int mi = 0; mi < 2; ++mi) for (int ni = 0; ni < 4; ++ni) sc[mi][ni] = z;
  for (int kc = 0; kc < 2; ++kc){
    bf16x8 aq[2], bk[4];
    for (int mi = 0; mi < 2; ++mi)
      aq[mi] = *(const bf16x8*)&Qs[(w * 32 + mi * 16 + md) * 72 + kc * 32 + qd * 8];
    for (int ni = 0; ni < 4; ++ni)
      bk[ni] = *(const bf16x8*)&Ks[(ni * 16 + md) * 72 + kc * 32 + qd * 8];
    for (int mi = 0; mi < 2; ++mi)
      for (int ni = 0; ni < 4; ++ni)
        sc[mi][ni] = __builtin_amdgcn_mfma_f32_16x16x32_bf16(aq[mi], bk[ni], sc[mi][ni], 0, 0, 0);
  }

  // softmax over 64 keys; scale 1/sqrt(64)=0.125. Row r lives in 16 lanes
  // (same quad) x 4 col-tiles -> in-register + shfl_xor(1,2,4,8) reduction.
  const float scale = 0.125f;
  ushort_t* Ps = Qs;  // alias: wave only touches its own 32 rows
  for (int mi = 0; mi < 2; ++mi){
    for (int i = 0; i < 4; ++i){
      float mx = sc[mi][0][i];
      for (int ni = 1; ni < 4; ++ni) mx = fmaxf(mx, sc[mi][ni][i]);
      for (int d = 1; d < 16; d <<= 1) mx = fmaxf(mx, __shfl_xor(mx, d));
      float e[4], sum = 0.f;
      for (int ni = 0; ni < 4; ++ni){ e[ni] = __expf((sc[mi][ni][i] - mx) * scale); sum += e[ni]; }
      for (int d = 1; d < 16; d <<= 1) sum += __shfl_xor(sum, d);
      float inv = 1.0f / sum;
      int r = w * 32 + mi * 16 + qd * 4 + i;
      for (int ni = 0; ni < 4; ++ni)
        Ps[r * 72 + ni * 16 + md] = f2bf(e[ni] * inv);
    }
  }

  // O = P @ V : A = P (rows w*32..+31), B = Vt[d][k]
  f32x4 oc[2][4];
  for (int mi = 0; mi < 2; ++mi) for (int ni = 0; ni < 4; ++ni) oc[mi][ni] = z;
  for (int kc = 0; kc < 2; ++kc){
    bf16x8 ap[2], bv[4];
    for (int mi = 0; mi < 2; ++mi)
      ap[mi] = *(const bf16x8*)&Ps[(w * 32 + mi * 16 + md) * 72 + kc * 32 + qd * 8];
    for (int ni = 0; ni < 4; ++ni)
      bv[ni] = *(const bf16x8*)&Vt[(ni * 16 + md) * 72 + kc * 32 + qd * 8];
    for (int mi = 0; mi < 2; ++mi)
      for (int ni = 0; ni < 4; ++ni)
        oc[mi][ni] = __builtin_amdgcn_mfma_f32_16x16x32_bf16(ap[mi], bv[ni], oc[mi][ni], 0, 0, 0);
  }

  // O back into wave-private LDS rows (overwrites this wave's P), then
  // one barrier and fully-coalesced 16B stores: row s=hmap(p0+r), 128B/row.
  for (int mi = 0; mi < 2; ++mi){
    for (int i = 0; i < 4; ++i){
      int rl = w * 32 + mi * 16 + qd * 4 + i;
      for (int ni = 0; ni < 4; ++ni)
        Ps[rl * 72 + ni * 16 + md] = f2bf(oc[mi][ni][i]);
    }
  }
  __syncthreads();
  for (int it = 0; it < 4; ++it){
    int q = it * 256 + tid;
    int r = q >> 3, ch = q & 7;
    int s = hmap(p0 + r);
    *(uint4*)&aout[(size_t)(b * 8192 + s) * 1024 + h * 64 + ch * 8] =
        *(const uint4*)&Qs[r * 72 + ch * 8];
  }
}

extern "C" void kernel_launch(void* const* d_in, const int* in_sizes, int n_in,
                              void* d_out, int out_size, void* d_ws, size_t ws_size,
                              hipStream_t stream){
  const float* x    = (const float*)d_in[0];   // [2,8192,1024]
  const float* Wqkv = (const float*)d_in[1];   // [1024,3072]
  const float* Wout = (const float*)d_in[2];   // [1024,1024]
  float* out = (float*)d_out;                  // [2,8192,1024]

  // ws layout (bytes): xb 32M | WqT 6M | WoT 2M | Qbuf 32M | KVbuf 32M | aout 32M = 136 MB
  char* ws = (char*)d_ws;
  ushort_t* xb    = (ushort_t*)(ws);
  ushort_t* WqT   = (ushort_t*)(ws + 33554432);
  ushort_t* WoT   = (ushort_t*)(ws + 39845888);
  ushort_t* Qbuf  = (ushort_t*)(ws + 41943040);
  ushort_t* KVbuf = (ushort_t*)(ws + 75497472);
  ushort_t* aoutb = (ushort_t*)(ws + 109051904);

  cast_kernel<<<16384, 256, 0, stream>>>(x, xb, (16384 * 1024) / 4);
  transpose_cast<<<dim3(48, 16), 256, 0, stream>>>(Wqkv, WqT, 1024, 3072);
  transpose_cast<<<dim3(16, 16), 256, 0, stream>>>(Wout, WoT, 1024, 1024);
  // Q projection: grid = (16384/256)*(1024/256) = 256 = 1 block/CU
  gemm_bt<1, 1><<<dim3(256), dim3(512), 0, stream>>>(xb, WqT, Qbuf, 16384, 1024, 1024);
  // K,V projection: (8192/256)*(2048/256) = 256
  gemm_bt<1, 2><<<dim3(256), dim3(512), 0, stream>>>(xb, WqT + (size_t)1024 * 1024, KVbuf, 8192, 2048, 1024);
  attn_kernel<<<dim3(64, 16, 2), 256, 0, stream>>>(Qbuf, KVbuf, aoutb);
  // output projection: 256
  gemm_bt<0, 0><<<dim3(256), dim3(512), 0, stream>>>(aoutb, WoT, out, 16384, 1024, 1024);
}

// Round 3
// 264.816 us; speedup vs baseline: 1.4497x; 1.4497x over previous
//
#include <hip/hip_runtime.h>
#include <stdint.h>

typedef unsigned short ushort_t;
typedef __bf16 bf16x8 __attribute__((ext_vector_type(8)));
typedef float  f32x4  __attribute__((ext_vector_type(4)));

#define DEV static __device__ __forceinline__

// fp32 -> bf16 round-to-nearest-even
DEV ushort_t f2bf(float f){
  union { float f; unsigned u; } x; x.f = f;
  unsigned u = x.u;
  return (ushort_t)((u + 0x7fffu + ((u >> 16) & 1u)) >> 16);
}

// Boustrophedon map for S=8192 (g=91): involution, maps permuted<->original.
DEV int hmap(int p){
  int r = p / 91;
  int c = p - r * 91;
  return (r & 1) ? (r * 91 + 90 - c) : p;
}

// A-row gather modes: 0 identity; 1 = Q permuted order; 2 = compacted dilated KV.
template<int GATHER>
DEV int arow_map(int r){
  if (GATHER == 0) return r;
  if (GATHER == 1){ int b = r >> 13, p = r & 8191; return b * 8192 + hmap(p); }
  int b = r >> 12, rem = r & 4095, seg = rem >> 6, j = rem & 63;
  return b * 8192 + hmap(seg * 128 + 2 * j);
}

// async global->LDS 16B per lane (LDS dest must be uniform base + lane*16)
DEV void async16(const void* g, void* l){
  __builtin_amdgcn_global_load_lds(
      (const __attribute__((address_space(1))) unsigned*)g,
      (__attribute__((address_space(3))) unsigned*)l, 16, 0, 0);
}

// ---------------- cast x (fp32 -> bf16), vectorized, grid-stride ----------------
__global__ void cast_kernel(const float* __restrict__ in, ushort_t* __restrict__ out, int n4){
  int stride = gridDim.x * blockDim.x;
  for (int i = blockIdx.x * blockDim.x + threadIdx.x; i < n4; i += stride){
    float4 v = ((const float4*)in)[i];
    ushort4 o;
    o.x = f2bf(v.x); o.y = f2bf(v.y); o.z = f2bf(v.z); o.w = f2bf(v.w);
    ((ushort4*)out)[i] = o;
  }
}

// ---------- transpose + cast: W [rows][cols] fp32 -> WT [cols][rows] bf16 ----------
__global__ void transpose_cast(const float* __restrict__ W, ushort_t* __restrict__ WT,
                               int rows, int cols){
  __shared__ ushort_t t[64 * 66];   // pad 66: conflict-free column reads
  int tid = threadIdx.x;
  int c0 = blockIdx.x * 64, r0 = blockIdx.y * 64;
  int cl = tid & 63, rb = tid >> 6;
  for (int i = 0; i < 16; ++i){
    int r = rb + i * 4;
    t[r * 66 + cl] = f2bf(W[(size_t)(r0 + r) * cols + c0 + cl]);
  }
  __syncthreads();
  int rr = tid & 63, cb = tid >> 6;
  for (int i = 0; i < 16; ++i){
    int cc = cb + i * 4;
    WT[(size_t)(c0 + cc) * rows + r0 + rr] = t[rr * 66 + cc];
  }
}

// ================= 256x256 8-phase GEMM, SEPARATE LDS OBJECTS =================
// C[M][N] = A[gather(M)][K] * BT[N][K]^T. BM=BN=256, BK=64, 512 thr (8 waves,
// 2Mx4N, wave tile 128x64).
//
// R0/R1 post-mortem: both drain-per-slab AND 8-phase-counted landed at exactly
// 48 us -> one shared limiter. Theory: LLVM's waitcnt pass tracks LDS-DMA
// (global_load_lds) targets PER LDS OBJECT; with double-buffering inside one
// __shared__ array it cannot prove ds_read(buf[t]) disjoint from outstanding
// DMA into buf[t+1] -> inserts a vmcnt drain before every phase's fragment
// reads -> per-tile latency exposure regardless of source-level schedule.
//
// Fix: FOUR separate __shared__ arrays As0/As1/Bs0/Bs1, 2-tile-unrolled loop
// so buffer choice is compile-time and every ds_read indexes its array
// directly (object-granular no-alias). Staging is 1 tile ahead: A(t+1) at
// phase0, B(t+1) at phase1; the only vmcnt(0) sits at the tile boundary,
// ~2000cy after the last issue -> satisfied-by-construction (no real drain).
// All compute ds_reads target tile-t objects while all outstanding DMAs
// target tile-(t+1) objects. Raw s_barrier; setprio(1) around MFMA clusters.
// If AA fails this degenerates to R1's measured 48us (safe).
//
// LDS swizzle: row of 64 bf16 = 8x16B chunks; LDS slot s holds global chunk
// s^(row&7) (pre-swizzled global source; DMA dest stays linear). Fragment
// reads use the same XOR -> 0 bank conflicts (verified R1).
// Block map: plain n-major (R0's measured-low FETCH: B panel shared chip-wide,
// A panels stream per-block, L3 absorbs A re-reads).

#define BARRIER() asm volatile("s_barrier" ::: "memory")
#define LGKM0()   asm volatile("s_waitcnt lgkmcnt(0)" ::: "memory")
#define VMCNT0()  asm volatile("s_waitcnt vmcnt(0)" ::: "memory")

#define STAGE_A_TO(DST, T1)                                                    \
  if ((T1) < NT){                                                              \
    _Pragma("unroll") for (int i = 0; i < 4; ++i)                              \
      async16(&A[asrcR[i] + (size_t)(T1) * 64], &DST[i * 4096 + tid * 8]);     \
  }

#define STAGE_B_TO(DST, T1)                                                    \
  if ((T1) < NT){                                                              \
    _Pragma("unroll") for (int i = 0; i < 4; ++i)                              \
      async16(&BT[bsrcR[i] + (size_t)(T1) * 64], &DST[i * 4096 + tid * 8]);    \
  }

#define READ_AF(ABUF, MI0)                                                     \
  _Pragma("unroll") for (int m2 = 0; m2 < 2; ++m2)                             \
    _Pragma("unroll") for (int kk = 0; kk < 2; ++kk)                           \
      af[m2][kk] = *(const bf16x8*)&ABUF[(wm * 128 + ((MI0) + m2) * 16 + md) * 64 + axor[kk]];

#define MFMA16(MI0)                                                            \
  __builtin_amdgcn_s_setprio(1);                                               \
  _Pragma("unroll") for (int kk = 0; kk < 2; ++kk)                             \
    _Pragma("unroll") for (int ni = 0; ni < 4; ++ni)                           \
      _Pragma("unroll") for (int m2 = 0; m2 < 2; ++m2)                         \
        acc[(MI0) + m2][ni] = __builtin_amdgcn_mfma_f32_16x16x32_bf16(         \
            af[m2][kk], bv[ni][kk], acc[(MI0) + m2][ni], 0, 0, 0);             \
  __builtin_amdgcn_s_setprio(0);

#define TILE(T, CUR, NXT)                                                      \
  {                                                                            \
    bf16x8 af[2][2], bv[4][2];                                                 \
    _Pragma("unroll") for (int ni = 0; ni < 4; ++ni)                           \
      _Pragma("unroll") for (int kk = 0; kk < 2; ++kk)                         \
        bv[ni][kk] = *(const bf16x8*)&Bs##CUR[(wn * 64 + ni * 16 + md) * 64 + axor[kk]]; \
    READ_AF(As##CUR, 0);                                                       \
    STAGE_A_TO(As##NXT, (T) + 1);                                              \
    BARRIER(); LGKM0(); MFMA16(0); BARRIER();                                  \
    READ_AF(As##CUR, 2);                                                       \
    STAGE_B_TO(Bs##NXT, (T) + 1);                                              \
    BARRIER(); LGKM0(); MFMA16(2); BARRIER();                                  \
    READ_AF(As##CUR, 4);                                                       \
    BARRIER(); LGKM0(); MFMA16(4); BARRIER();                                  \
    READ_AF(As##CUR, 6);                                                       \
    BARRIER(); LGKM0(); MFMA16(6); VMCNT0(); BARRIER();                        \
  }

template<int OUT_BF16, int GATHER>
__global__ __launch_bounds__(512, 2) void gemm_bt(const ushort_t* __restrict__ A,
                                                  const ushort_t* __restrict__ BT,
                                                  void* __restrict__ Cout,
                                                  int M, int N, int K){
  __shared__ __align__(16) ushort_t As0[16384];
  __shared__ __align__(16) ushort_t As1[16384];
  __shared__ __align__(16) ushort_t Bs0[16384];
  __shared__ __align__(16) ushort_t Bs1[16384];
  const int NT = K >> 6;                           // K-tiles (=16, even)
  int tid = threadIdx.x;
  int lane = tid & 63, w = tid >> 6;
  int md = lane & 15, qd = lane >> 4;
  int wm = w >> 2, wn = w & 3;

  // n-major block map (R0's measured-low FETCH)
  int o = blockIdx.x;
  int mtc = M >> 8;
  int nt = o / mtc, mt = o - nt * mtc;
  int m0 = mt << 8, n0 = nt << 8;

  // staging: thread covers LDS rows i*64 + (tid>>3), slot tid&7; global chunk
  // g0 = slot ^ (row&7)  ((64*i)&7==0 so g0 is i-independent)
  int rbase = tid >> 3;
  int g0 = ((tid & 7) ^ (rbase & 7)) * 8;          // elems
  size_t asrcR[4], bsrcR[4];
  #pragma unroll
  for (int i = 0; i < 4; ++i){
    asrcR[i] = (size_t)arow_map<GATHER>(m0 + i * 64 + rbase) * K + g0;
    bsrcR[i] = (size_t)(n0 + i * 64 + rbase) * K + g0;
  }

  // fragment offsets: frag row = (multiple of 8) + md -> row&7 == md&7
  int axor[2] = { (qd ^ (md & 7)) * 8, ((4 + qd) ^ (md & 7)) * 8 };

  f32x4 acc[8][4];
  #pragma unroll
  for (int a = 0; a < 8; ++a)
    #pragma unroll
    for (int b = 0; b < 4; ++b)
      #pragma unroll
      for (int e = 0; e < 4; ++e) acc[a][b][e] = 0.f;

  // prologue: tile 0 into buffers 0
  STAGE_A_TO(As0, 0);
  STAGE_B_TO(Bs0, 0);
  VMCNT0(); BARRIER();

  for (int t = 0; t < NT; t += 2){
    TILE(t,     0, 1);
    TILE(t + 1, 1, 0);
  }

  // epilogue: 16x16 C/D layout col=lane&15, row=(lane>>4)*4+reg
  int crow0 = m0 + wm * 128 + qd * 4;
  int ccol0 = n0 + wn * 64 + md;
  #pragma unroll
  for (int mi = 0; mi < 8; ++mi){
    #pragma unroll
    for (int ni = 0; ni < 4; ++ni){
      f32x4 v = acc[mi][ni];
      #pragma unroll
      for (int r = 0; r < 4; ++r){
        size_t idx = (size_t)(crow0 + mi * 16 + r) * N + ccol0 + ni * 16;
        if (OUT_BF16) ((ushort_t*)Cout)[idx] = f2bf(v[r]);
        else          ((float*)   Cout)[idx] = v[r];
      }
    }
  }
}

// ---------------- fused segment attention ----------------
// grid (nseg=64, H=16, B=2), block 256 (4 waves).
// Qb:  [B*8192][1024] bf16, rows already in PERMUTED order (gemm1a GATHER=1).
// KV:  [B*4096][2048] bf16, rows in compacted dilated order seg*64+j
//      (gemm1b GATHER=2); cols 0..1023 = K, 1024..2047 = V.
// Vt stores V transposed with a k-chunk XOR swizzle: plain stride-72 layout
// put all 8 chunk-lanes of the transpose-store in ONE bank (d-stride 144B,
// 144*8 % 128 == 0 -> 8-way conflict x8 elems). Swizzle: k-chunk ^= (d>>3)&7.
__global__ __launch_bounds__(256) void attn_kernel(const ushort_t* __restrict__ Qb,
                                                   const ushort_t* __restrict__ KV,
                                                   ushort_t* __restrict__ aout){
  __shared__ ushort_t Qs[128 * 72];   // reused as P, then as O (wave-private rows)
  __shared__ ushort_t Ks[64 * 72];
  __shared__ ushort_t Vt[64 * 72];    // V transposed: Vt[d][k], k-chunk swizzled
  int tid  = threadIdx.x;
  int lane = tid & 63, w = tid >> 6;
  int qd = lane >> 4, md = lane & 15;
  int seg = blockIdx.x, h = blockIdx.y, b = blockIdx.z;
  int p0 = seg * 128;

  // Q: 128 rows x 64 bf16 (8 chunks of 16B per row), contiguous rows
  for (int it = 0; it < 4; ++it){
    int q = it * 256 + tid;
    int r = q >> 3, ch = q & 7;
    uint4 d = *(const uint4*)&Qb[(size_t)(b * 8192 + p0 + r) * 1024 + h * 64 + ch * 8];
    *(uint4*)&Qs[r * 72 + ch * 8] = d;
  }
  // K: compacted rows seg*64 + r
  for (int it = 0; it < 2; ++it){
    int q = it * 256 + tid;
    int r = q >> 3, ch = q & 7;
    uint4 d = *(const uint4*)&KV[(size_t)(b * 4096 + seg * 64 + r) * 2048 + h * 64 + ch * 8];
    *(uint4*)&Ks[r * 72 + ch * 8] = d;
  }
  // V (cols 1024..2047), stored transposed with swizzled k-chunk:
  // element V[k=r][d=ch*8+e] -> Vt[d*72 + ((r>>3)^ch)*8 + (r&7)]
  for (int it = 0; it < 2; ++it){
    int q = it * 256 + tid;
    int r = q >> 3, ch = q & 7;
    union { uint4 v; ushort_t u[8]; } d;
    d.v = *(const uint4*)&KV[(size_t)(b * 4096 + seg * 64 + r) * 2048 + 1024 + h * 64 + ch * 8];
    int kslot = ((r >> 3) ^ ch) * 8 + (r & 7);
    for (int e = 0; e < 8; ++e) Vt[(ch * 8 + e) * 72 + kslot] = d.u[e];
  }
  __syncthreads();

  // scores: wave w owns q-rows [32w, 32w+32): 2 row-tiles x 4 col-tiles
  f32x4 z = {0.f, 0.f, 0.f, 0.f};
  f32x4 sc[2][4];
  for (int mi = 0; mi < 2; ++mi) for (int ni = 0; ni < 4; ++ni) sc[mi][ni] = z;
  for (int kc = 0; kc < 2; ++kc){
    bf16x8 aq[2], bk[4];
    for (int mi = 0; mi < 2; ++mi)
      aq[mi] = *(const bf16x8*)&Qs[(w * 32 + mi * 16 + md) * 72 + kc * 32 + qd * 8];
    for (int ni = 0; ni < 4; ++ni)
      bk[ni] = *(const bf16x8*)&Ks[(ni * 16 + md) * 72 + kc * 32 + qd * 8];
    for (int mi = 0; mi < 2; ++mi)
      for (int ni = 0; ni < 4; ++ni)
        sc[mi][ni] = __builtin_amdgcn_mfma_f32_16x16x32_bf16(aq[mi], bk[ni], sc[mi][ni], 0, 0, 0);
  }

  // softmax over 64 keys; scale 1/sqrt(64)=0.125. Row r lives in 16 lanes
  // (same quad) x 4 col-tiles -> in-register + shfl_xor(1,2,4,8) reduction.
  const float scale = 0.125f;
  ushort_t* Ps = Qs;  // alias: wave only touches its own 32 rows
  for (int mi = 0; mi < 2; ++mi){
    for (int i = 0; i < 4; ++i){
      float mx = sc[mi][0][i];
      for (int ni = 1; ni < 4; ++ni) mx = fmaxf(mx, sc[mi][ni][i]);
      for (int d = 1; d < 16; d <<= 1) mx = fmaxf(mx, __shfl_xor(mx, d));
      float e[4], sum = 0.f;
      for (int ni = 0; ni < 4; ++ni){ e[ni] = __expf((sc[mi][ni][i] - mx) * scale); sum += e[ni]; }
      for (int d = 1; d < 16; d <<= 1) sum += __shfl_xor(sum, d);
      float inv = 1.0f / sum;
      int r = w * 32 + mi * 16 + qd * 4 + i;
      for (int ni = 0; ni < 4; ++ni)
        Ps[r * 72 + ni * 16 + md] = f2bf(e[ni] * inv);
    }
  }

  // O = P @ V : A = P (rows w*32..+31), B = Vt[d][k] (k-chunk swizzled)
  f32x4 oc[2][4];
  for (int mi = 0; mi < 2; ++mi) for (int ni = 0; ni < 4; ++ni) oc[mi][ni] = z;
  for (int kc = 0; kc < 2; ++kc){
    bf16x8 ap[2], bv[4];
    for (int mi = 0; mi < 2; ++mi)
      ap[mi] = *(const bf16x8*)&Ps[(w * 32 + mi * 16 + md) * 72 + kc * 32 + qd * 8];
    for (int ni = 0; ni < 4; ++ni){
      int dd = ni * 16 + md;
      int vchunk = ((kc * 4 + qd) ^ ((dd >> 3) & 7)) & 7;
      bv[ni] = *(const bf16x8*)&Vt[dd * 72 + vchunk * 8];
    }
    for (int mi = 0; mi < 2; ++mi)
      for (int ni = 0; ni < 4; ++ni)
        oc[mi][ni] = __builtin_amdgcn_mfma_f32_16x16x32_bf16(ap[mi], bv[ni], oc[mi][ni], 0, 0, 0);
  }

  // O back into wave-private LDS rows (overwrites this wave's P), then
  // one barrier and fully-coalesced 16B stores: row s=hmap(p0+r), 128B/row.
  for (int mi = 0; mi < 2; ++mi){
    for (int i = 0; i < 4; ++i){
      int rl = w * 32 + mi * 16 + qd * 4 + i;
      for (int ni = 0; ni < 4; ++ni)
        Ps[rl * 72 + ni * 16 + md] = f2bf(oc[mi][ni][i]);
    }
  }
  __syncthreads();
  for (int it = 0; it < 4; ++it){
    int q = it * 256 + tid;
    int r = q >> 3, ch = q & 7;
    int s = hmap(p0 + r);
    *(uint4*)&aout[(size_t)(b * 8192 + s) * 1024 + h * 64 + ch * 8] =
        *(const uint4*)&Qs[r * 72 + ch * 8];
  }
}

extern "C" void kernel_launch(void* const* d_in, const int* in_sizes, int n_in,
                              void* d_out, int out_size, void* d_ws, size_t ws_size,
                              hipStream_t stream){
  const float* x    = (const float*)d_in[0];   // [2,8192,1024]
  const float* Wqkv = (const float*)d_in[1];   // [1024,3072]
  const float* Wout = (const float*)d_in[2];   // [1024,1024]
  float* out = (float*)d_out;                  // [2,8192,1024]

  // ws layout (bytes): xb 32M | WqT 6M | WoT 2M | Qbuf 32M | KVbuf 32M | aout 32M = 136 MB
  char* ws = (char*)d_ws;
  ushort_t* xb    = (ushort_t*)(ws);
  ushort_t* WqT   = (ushort_t*)(ws + 33554432);
  ushort_t* WoT   = (ushort_t*)(ws + 39845888);
  ushort_t* Qbuf  = (ushort_t*)(ws + 41943040);
  ushort_t* KVbuf = (ushort_t*)(ws + 75497472);
  ushort_t* aoutb = (ushort_t*)(ws + 109051904);

  cast_kernel<<<2048, 256, 0, stream>>>(x, xb, (16384 * 1024) / 4);
  transpose_cast<<<dim3(48, 16), 256, 0, stream>>>(Wqkv, WqT, 1024, 3072);
  transpose_cast<<<dim3(16, 16), 256, 0, stream>>>(Wout, WoT, 1024, 1024);
  // Q projection: grid = (16384/256)*(1024/256) = 256
  gemm_bt<1, 1><<<dim3(256), dim3(512), 0, stream>>>(xb, WqT, Qbuf, 16384, 1024, 1024);
  // K,V projection: (8192/256)*(2048/256) = 256
  gemm_bt<1, 2><<<dim3(256), dim3(512), 0, stream>>>(xb, WqT + (size_t)1024 * 1024, KVbuf, 8192, 2048, 1024);
  attn_kernel<<<dim3(64, 16, 2), 256, 0, stream>>>(Qbuf, KVbuf, aoutb);
  // output projection
  gemm_bt<0, 0><<<dim3(256), dim3(512), 0, stream>>>(aoutb, WoT, out, 16384, 1024, 1024);
}